// Round 1
// baseline (371.460 us; speedup 1.0000x reference)
//
#include <hip/hip_runtime.h>

#define NB 64
#define NB_ELEMS 2080   // 64*65/2
#define EPS 1e-7f

// One wave (64 lanes) per batch element. Lane j owns column j of L^T d.
// quad = d^T L L^T d = || L^T d ||^2 ; A = -0.5 * quad.
// L_flat is row-major packed lower triangle: (i,j) -> i*(i+1)/2 + j.
// Row-i pass: lanes j<=i load consecutive floats (coalesced), fma with
// broadcast d_i (readlane). Diagonal (j==i) gets exp(x)+eps via cndmask.
__global__ __launch_bounds__(256) void naf_quad_kernel(
    const float* __restrict__ L_flat,
    const float* __restrict__ mu,
    const float* __restrict__ a,
    float* __restrict__ out, int batch)
{
    const int lane = threadIdx.x & 63;
    const int wave = threadIdx.x >> 6;
    const int b = (blockIdx.x << 2) + wave;
    if (b >= batch) return;

    const float* __restrict__ Lb = L_flat + (size_t)b * NB_ELEMS;

    // d_j = a_j - mu_j  (coalesced 4B loads)
    const float d = a[(size_t)b * NB + lane] - mu[(size_t)b * NB + lane];

    // 4 partial accumulators to break the FMA dependence chain
    float yacc[4] = {0.f, 0.f, 0.f, 0.f};

#pragma unroll
    for (int i = 0; i < NB; ++i) {
        const int base = i * (i + 1) / 2;          // constant after unroll
        float x = Lb[base + lane];                  // lanes j>i: in-bounds junk, masked below
        float v = (lane == i) ? (__expf(x) + EPS) : x;
        v = (lane <= i) ? v : 0.f;
        const float di = __shfl(d, i);              // constant lane -> v_readlane (SGPR)
        yacc[i & 3] = fmaf(v, di, yacc[i & 3]);
    }

    const float y = (yacc[0] + yacc[1]) + (yacc[2] + yacc[3]);
    float q = y * y;

    // wave64 butterfly reduction
#pragma unroll
    for (int off = 32; off > 0; off >>= 1)
        q += __shfl_xor(q, off);

    if (lane == 0) out[b] = -0.5f * q;
}

extern "C" void kernel_launch(void* const* d_in, const int* in_sizes, int n_in,
                              void* d_out, int out_size, void* d_ws, size_t ws_size,
                              hipStream_t stream) {
    const float* L_flat = (const float*)d_in[0];
    const float* mu     = (const float*)d_in[1];
    const float* a      = (const float*)d_in[2];
    float* out = (float*)d_out;

    const int batch  = in_sizes[0] / NB_ELEMS;   // 32768
    const int blocks = (batch + 3) / 4;          // 4 waves/block, 1 batch/wave
    naf_quad_kernel<<<blocks, 256, 0, stream>>>(L_flat, mu, a, out, batch);
}

// Round 2
// 368.993 us; speedup vs baseline: 1.0067x; 1.0067x over previous
//
#include <hip/hip_runtime.h>

#define NB 64
#define NB_ELEMS 2080   // 64*65/2
#define EPS 1e-7f
#define TRI(i) ((i) * ((i) + 1) / 2)

// One wave per batch element; 4 waves / 256-block.
// quad = d^T L L^T d = ||L^T d||^2 ; y_j = L[j,j]*d_j + sum_{i>j} L[i,j]*d_i.
// Packed lower-tri row-major: (i,j) -> i*(i+1)/2 + j.
//
// Stage plan: global -> LDS with float4 coalesced loads (2080 floats = 520
// float4 = 8 full rounds + 8-lane tail). d staged in LDS for uniform-address
// broadcast reads (b128, 4 coeffs/read). exp() computed once per lane (its
// own diagonal). Inner loop: imm-offset ds_read_b32 + cndmask + fma only.
__global__ __launch_bounds__(256) void naf_quad_kernel(
    const float* __restrict__ L_flat,
    const float* __restrict__ mu,
    const float* __restrict__ a,
    float* __restrict__ out, int batch)
{
    __shared__ float sL[4 * NB_ELEMS];   // 33280 B, per-wave segments
    __shared__ float sd[4 * NB];         // 1024 B

    const int lane = threadIdx.x & 63;
    const int wave = threadIdx.x >> 6;
    const int b = (blockIdx.x << 2) + wave;
    const bool active = b < batch;

    float* __restrict__ wL = sL + wave * NB_ELEMS;
    float* __restrict__ wd = sd + wave * NB;

    if (active) {
        // ---- stage packed tril: 520 float4, coalesced 16B/lane ----
        const float4* __restrict__ Lb4 =
            (const float4*)(L_flat + (size_t)b * NB_ELEMS);
        float4* __restrict__ wL4 = (float4*)wL;   // 8320 B seg, 16B aligned
#pragma unroll
        for (int k = 0; k < 8; ++k)
            wL4[k * 64 + lane] = Lb4[k * 64 + lane];
        if (lane < 8)
            wL4[512 + lane] = Lb4[512 + lane];

        // ---- d = a - mu ----
        const float dv = a[(size_t)b * NB + lane] - mu[(size_t)b * NB + lane];
        wd[lane] = dv;
    }

    __syncthreads();   // cheap; guarantees LDS visibility before compute

    if (active) {
        const float dv = wd[lane];

        // diagonal: exactly one exp per lane (element tri(lane)+lane)
        const float ldiag = __expf(wL[TRI(lane) + lane]) + EPS;
        float y0 = ldiag * dv;
        float y1 = 0.f;

        // strict lower triangle: rows i = 1..63, lane j < i contributes
#pragma unroll
        for (int i0 = 0; i0 < NB; i0 += 4) {
            const float4 d4 = *(const float4*)(wd + i0);  // uniform broadcast
            const float dc[4] = {d4.x, d4.y, d4.z, d4.w};
#pragma unroll
            for (int k = 0; k < 4; ++k) {
                const int i = i0 + k;
                if (i == 0) continue;                 // row 0 has no off-diag
                const float x = wL[TRI(i) + lane];     // imm-offset ds_read
                const float v = (lane < i) ? x : 0.f;  // strict lower mask
                if (k & 1) y1 = fmaf(v, dc[k], y1);
                else       y0 = fmaf(v, dc[k], y0);
            }
        }

        float q = y0 + y1;
        q = q * q;

        // wave64 butterfly reduction of sum_j y_j^2
#pragma unroll
        for (int off = 32; off > 0; off >>= 1)
            q += __shfl_xor(q, off);

        if (lane == 0) out[b] = -0.5f * q;
    }
}

extern "C" void kernel_launch(void* const* d_in, const int* in_sizes, int n_in,
                              void* d_out, int out_size, void* d_ws, size_t ws_size,
                              hipStream_t stream) {
    const float* L_flat = (const float*)d_in[0];
    const float* mu     = (const float*)d_in[1];
    const float* a      = (const float*)d_in[2];
    float* out = (float*)d_out;

    const int batch  = in_sizes[0] / NB_ELEMS;   // 32768
    const int blocks = (batch + 3) / 4;          // 4 waves/block, 1 batch/wave
    naf_quad_kernel<<<blocks, 256, 0, stream>>>(L_flat, mu, a, out, batch);
}

// Round 3
// 347.377 us; speedup vs baseline: 1.0693x; 1.0622x over previous
//
#include <hip/hip_runtime.h>

#define NB 64
#define NB_ELEMS 2080   // 64*65/2
#define EPS 1e-7f
#define TRI(i) ((i) * ((i) + 1) / 2)

typedef float f4 __attribute__((ext_vector_type(4)));

// One wave per batch element; 4 waves / 256-block.
// quad = d^T L L^T d = ||L^T d||^2 ; y_j = L[j,j]*d_j + sum_{i>j} L[i,j]*d_i.
// Packed lower-tri row-major: (i,j) -> i*(i+1)/2 + j.
//
// All global inputs are read exactly once -> nontemporal loads (skip cache
// allocate). Stage tril into LDS via coalesced 16B loads, d into LDS for
// uniform-address broadcast. exp() once per lane (own diagonal). Inner loop:
// imm-offset ds_read_b32 + cndmask + fma.
__global__ __launch_bounds__(256) void naf_quad_kernel(
    const float* __restrict__ L_flat,
    const float* __restrict__ mu,
    const float* __restrict__ a,
    float* __restrict__ out, int batch)
{
    __shared__ float sL[4 * NB_ELEMS];   // 33280 B, per-wave segments
    __shared__ float sd[4 * NB];         // 1024 B

    const int lane = threadIdx.x & 63;
    const int wave = threadIdx.x >> 6;
    const int b = (blockIdx.x << 2) + wave;
    const bool active = b < batch;

    float* __restrict__ wL = sL + wave * NB_ELEMS;
    float* __restrict__ wd = sd + wave * NB;

    if (active) {
        // ---- stage packed tril: 520 f4, coalesced 16B/lane, nontemporal ----
        const f4* __restrict__ Lb4 = (const f4*)(L_flat + (size_t)b * NB_ELEMS);
        f4* __restrict__ wL4 = (f4*)wL;   // 8320 B seg (520*16), 16B aligned
#pragma unroll
        for (int k = 0; k < 8; ++k)
            wL4[k * 64 + lane] = __builtin_nontemporal_load(&Lb4[k * 64 + lane]);
        if (lane < 8)
            wL4[512 + lane] = __builtin_nontemporal_load(&Lb4[512 + lane]);

        // ---- d = a - mu (read-once, nontemporal) ----
        const float av = __builtin_nontemporal_load(&a[(size_t)b * NB + lane]);
        const float mv = __builtin_nontemporal_load(&mu[(size_t)b * NB + lane]);
        wd[lane] = av - mv;
    }

    __syncthreads();

    if (active) {
        const float dv = wd[lane];

        // diagonal: exactly one exp per lane (element tri(lane)+lane)
        const float ldiag = __expf(wL[TRI(lane) + lane]) + EPS;
        float y0 = ldiag * dv;
        float y1 = 0.f;

        // strict lower triangle: rows i = 1..63, lane j < i contributes
#pragma unroll
        for (int i0 = 0; i0 < NB; i0 += 4) {
            const float4 d4 = *(const float4*)(wd + i0);  // uniform broadcast
            const float dc[4] = {d4.x, d4.y, d4.z, d4.w};
#pragma unroll
            for (int k = 0; k < 4; ++k) {
                const int i = i0 + k;
                if (i == 0) continue;                 // row 0 has no off-diag
                const float x = wL[TRI(i) + lane];     // imm-offset ds_read
                const float v = (lane < i) ? x : 0.f;  // strict lower mask
                if (k & 1) y1 = fmaf(v, dc[k], y1);
                else       y0 = fmaf(v, dc[k], y0);
            }
        }

        float q = y0 + y1;
        q = q * q;

        // wave64 butterfly reduction of sum_j y_j^2
#pragma unroll
        for (int off = 32; off > 0; off >>= 1)
            q += __shfl_xor(q, off);

        if (lane == 0) __builtin_nontemporal_store(-0.5f * q, &out[b]);
    }
}

extern "C" void kernel_launch(void* const* d_in, const int* in_sizes, int n_in,
                              void* d_out, int out_size, void* d_ws, size_t ws_size,
                              hipStream_t stream) {
    const float* L_flat = (const float*)d_in[0];
    const float* mu     = (const float*)d_in[1];
    const float* a      = (const float*)d_in[2];
    float* out = (float*)d_out;

    const int batch  = in_sizes[0] / NB_ELEMS;   // 32768
    const int blocks = (batch + 3) / 4;          // 4 waves/block, 1 batch/wave
    naf_quad_kernel<<<blocks, 256, 0, stream>>>(L_flat, mu, a, out, batch);
}